// Round 5
// baseline (239.525 us; speedup 1.0000x reference)
//
#include <hip/hip_runtime.h>
#include <cstdint>

#define N_SEQ 8
#define B_DIM 64
#define H_DIM 128
#define F_DIM 256
#define HS 64

typedef __attribute__((ext_vector_type(8))) short short8;
typedef __attribute__((ext_vector_type(4))) float floatx4;

__device__ __forceinline__ ushort f2bf(float f) {
    union { float f; uint32_t u; } v; v.f = f;
    uint32_t r = v.u + 0x7FFF + ((v.u >> 16) & 1);   // RNE
    return (ushort)(r >> 16);
}

// ---------------- W transpose + cast: Wtb[n=192][k=256] bf16 ----------------
__global__ __launch_bounds__(256) void prep_w(
    const float* __restrict__ Wq, const float* __restrict__ Wk,
    const float* __restrict__ Wv, ushort* __restrict__ Wtb)
{
    const int n = blockIdx.x;                 // 0..191
    const float* W = (n < 64) ? Wq : (n < 128) ? Wk : Wv;
    const int c = n & 63;
    const int k = threadIdx.x;                // 0..255
    Wtb[n * 256 + k] = f2bf(W[k * 64 + c]);
}

// ---------------- QKV projection via MFMA ----------------
// 2048 blocks x 32 rows. 4 waves; wave w owns n-slice [w*48, w*48+48).
// Qb pre-scaled by log2(e)/16 (folds softmax scale + exp2 conversion).
#define XS_STRIDE 264   // 256 + 8 pad (bf16 elems)
__global__ __launch_bounds__(256, 6) void proj_mfma(
    const float* __restrict__ x, const ushort* __restrict__ Wtb,
    ushort* __restrict__ Qb, ushort* __restrict__ Kb, ushort* __restrict__ Vtb)
{
    __shared__ ushort xs[32 * XS_STRIDE];     // 16,896 B
    const int t = threadIdx.x;
    const int blk = blockIdx.x;
    const int64_t row0 = (int64_t)blk * 32;

    // stage x (fp32) -> xs (bf16): 32x256 elems, 1024 chunks of 8
    const float4* xg = (const float4*)(x + row0 * F_DIM);
    #pragma unroll
    for (int u = 0; u < 4; ++u) {
        const int idx = t + 256 * u;
        const int row = idx >> 5;
        const int c8 = (idx & 31) * 8;
        const float4 a = xg[idx * 2];
        const float4 b = xg[idx * 2 + 1];
        *(ushort4*)&xs[row * XS_STRIDE + c8] =
            make_ushort4(f2bf(a.x), f2bf(a.y), f2bf(a.z), f2bf(a.w));
        *(ushort4*)&xs[row * XS_STRIDE + c8 + 4] =
            make_ushort4(f2bf(b.x), f2bf(b.y), f2bf(b.z), f2bf(b.w));
    }
    __syncthreads();

    const int w = t >> 6, lane = t & 63;
    const int q16 = lane >> 4, l16 = lane & 15;
    const int n0 = w * 48;

    floatx4 acc[2][3];
    #pragma unroll
    for (int mt = 0; mt < 2; ++mt)
        #pragma unroll
        for (int nt = 0; nt < 3; ++nt) acc[mt][nt] = (floatx4){0.f, 0.f, 0.f, 0.f};

    short8 nb[3];
    #pragma unroll
    for (int nt = 0; nt < 3; ++nt)
        nb[nt] = *(const short8*)&Wtb[(n0 + nt * 16 + l16) * 256 + q16 * 8];

    for (int ks = 0; ks < 8; ++ks) {
        short8 cur[3];
        #pragma unroll
        for (int nt = 0; nt < 3; ++nt) cur[nt] = nb[nt];
        if (ks < 7) {
            #pragma unroll
            for (int nt = 0; nt < 3; ++nt)
                nb[nt] = *(const short8*)&Wtb[(n0 + nt * 16 + l16) * 256 + (ks + 1) * 32 + q16 * 8];
        }
        #pragma unroll
        for (int mt = 0; mt < 2; ++mt) {
            const short8 afr = *(const short8*)&xs[(mt * 16 + l16) * XS_STRIDE + ks * 32 + q16 * 8];
            #pragma unroll
            for (int nt = 0; nt < 3; ++nt)
                acc[mt][nt] = __builtin_amdgcn_mfma_f32_16x16x32_bf16(afr, cur[nt], acc[mt][nt], 0, 0, 0);
        }
    }

    // epilogue: Q scaled log2e/16; K row-major; V transposed Vtb[ib*64+d][h]
    const float qscale = 0.0625f * 1.44269504f;
    #pragma unroll
    for (int mt = 0; mt < 2; ++mt) {
        const int64_t g = row0 + mt * 16 + q16 * 4;   // global row of reg r=0
        #pragma unroll
        for (int nt = 0; nt < 3; ++nt) {
            const int ntb = n0 + nt * 16;             // wave-uniform
            const int n = ntb + l16;
            if (ntb < 64) {
                #pragma unroll
                for (int r = 0; r < 4; ++r)
                    Qb[(g + r) * 64 + n] = f2bf(acc[mt][nt][r] * qscale);
            } else if (ntb < 128) {
                #pragma unroll
                for (int r = 0; r < 4; ++r)
                    Kb[(g + r) * 64 + (n - 64)] = f2bf(acc[mt][nt][r]);
            } else {
                const int d = n - 128;
                const int ib = (int)(g >> 7);
                const int h = (int)(g & 127);
                *(ushort4*)&Vtb[((int64_t)(ib * 64 + d)) * 128 + h] =
                    make_ushort4(f2bf(acc[mt][nt][0]), f2bf(acc[mt][nt][1]),
                                 f2bf(acc[mt][nt][2]), f2bf(acc[mt][nt][3]));
            }
        }
    }
}

// ---------------- attention via MFMA, barrier-free ----------------
// 1024 blocks: blk = jb*2 + hh; 64 q-rows per block, wave owns 16.
// K and V fragments loaded DIRECTLY from global (L1/L2-hot) — no staging,
// no __syncthreads anywhere. Only wave-private Ps in LDS.
#define PS_STRIDE 36    // 32 + 4 pad (bf16 elems)
__global__ __launch_bounds__(256, 4) void attn_mfma(
    const ushort* __restrict__ Qb, const ushort* __restrict__ Kb,
    const ushort* __restrict__ Vtb, float* __restrict__ out)
{
    __shared__ ushort Ps[4][16 * PS_STRIDE]; //  4,608 B total

    const int t = threadIdx.x;
    const int blk = blockIdx.x;
    const int jb = blk >> 1;
    const int hh = blk & 1;
    const int b = jb & 63;
    const int w = t >> 6, lane = t & 63;
    const int q16 = lane >> 4, l16 = lane & 15;
    ushort* Psw = &Ps[w][0];

    // Q A-frags (Qb already scaled by log2e/16); wave rows = hh*64 + w*16 + [0,16)
    const int qrow0 = jb * H_DIM + hh * 64 + w * 16;
    short8 qa[2];
    #pragma unroll
    for (int ks = 0; ks < 2; ++ks)
        qa[ks] = *(const short8*)&Qb[(qrow0 + l16) * 64 + ks * 32 + q16 * 8];

    floatx4 of[4];
    #pragma unroll
    for (int nt = 0; nt < 4; ++nt) of[nt] = (floatx4){0.f, 0.f, 0.f, 0.f};

    for (int i = 0; i < N_SEQ; ++i) {
        const ushort* __restrict__ Kt = Kb + (int64_t)(i * B_DIM + b) * H_DIM * HS;
        const ushort* __restrict__ Vt = Vtb + (int64_t)(i * B_DIM + b) * HS * H_DIM;

        // ---- S' = (Q log2e/16) K^T : 16x128 per wave, B-frags direct from global ----
        floatx4 sf[8];
        #pragma unroll
        for (int nt = 0; nt < 8; ++nt) sf[nt] = (floatx4){0.f, 0.f, 0.f, 0.f};
        #pragma unroll
        for (int ks = 0; ks < 2; ++ks)
            #pragma unroll
            for (int nt = 0; nt < 8; ++nt) {
                const short8 bk = *(const short8*)&Kt[(nt * 16 + l16) * HS + ks * 32 + q16 * 8];
                sf[nt] = __builtin_amdgcn_mfma_f32_16x16x32_bf16(qa[ks], bk, sf[nt], 0, 0, 0);
            }

        // ---- softmax (no max-sub; scores bounded): P = 2^S' / sum ----
        #pragma unroll
        for (int nt = 0; nt < 8; ++nt)
            #pragma unroll
            for (int r = 0; r < 4; ++r) sf[nt][r] = __builtin_amdgcn_exp2f(sf[nt][r]);

        float inv[4];
        #pragma unroll
        for (int r = 0; r < 4; ++r) {
            float l = 0.f;
            #pragma unroll
            for (int nt = 0; nt < 8; ++nt) l += sf[nt][r];
            #pragma unroll
            for (int msk = 1; msk < 16; msk <<= 1) l += __shfl_xor(l, msk);
            inv[r] = __builtin_amdgcn_rcpf(l);
        }

        // ---- O += P V, kq-chunked through wave-private Ps; V direct from global ----
        #pragma unroll
        for (int kq = 0; kq < 4; ++kq) {
            #pragma unroll
            for (int nt2 = 0; nt2 < 2; ++nt2) {
                const int nt = kq * 2 + nt2;
                #pragma unroll
                for (int r = 0; r < 4; ++r)
                    Psw[(q16 * 4 + r) * PS_STRIDE + nt2 * 16 + l16] = f2bf(sf[nt][r] * inv[r]);
            }
            const short8 ap = *(const short8*)&Psw[l16 * PS_STRIDE + q16 * 8];
            #pragma unroll
            for (int nt = 0; nt < 4; ++nt) {
                const short8 bv = *(const short8*)&Vt[(nt * 16 + l16) * H_DIM + kq * 32 + q16 * 8];
                of[nt] = __builtin_amdgcn_mfma_f32_16x16x32_bf16(ap, bv, of[nt], 0, 0, 0);
            }
        }
    }

    // ---- epilogue ----
    #pragma unroll
    for (int nt = 0; nt < 4; ++nt)
        #pragma unroll
        for (int r = 0; r < 4; ++r)
            out[((int64_t)qrow0 + q16 * 4 + r) * HS + nt * 16 + l16] = of[nt][r];
}

extern "C" void kernel_launch(void* const* d_in, const int* in_sizes, int n_in,
                              void* d_out, int out_size, void* d_ws, size_t ws_size,
                              hipStream_t stream)
{
    const float* x  = (const float*)d_in[0];
    const float* Wq = (const float*)d_in[1];
    const float* Wk = (const float*)d_in[2];
    const float* Wv = (const float*)d_in[3];
    float* out = (float*)d_out;

    const size_t qkv = (size_t)N_SEQ * B_DIM * H_DIM * HS;   // 4,194,304 elems
    ushort* Qb  = (ushort*)d_ws;
    ushort* Kb  = Qb + qkv;
    ushort* Vtb = Kb + qkv;
    ushort* Wtb = Vtb + qkv;                                 // 192*256 elems

    prep_w<<<192, 256, 0, stream>>>(Wq, Wk, Wv, Wtb);
    proj_mfma<<<(N_SEQ * B_DIM * H_DIM) / 32, 256, 0, stream>>>(x, Wtb, Qb, Kb, Vtb);
    attn_mfma<<<N_SEQ * B_DIM * 2, 256, 0, stream>>>(Qb, Kb, Vtb, out);
}

// Round 6
// 205.392 us; speedup vs baseline: 1.1662x; 1.1662x over previous
//
#include <hip/hip_runtime.h>
#include <cstdint>

#define N_SEQ 8
#define B_DIM 64
#define H_DIM 128
#define F_DIM 256
#define HS 64

typedef __attribute__((ext_vector_type(8))) short short8;
typedef __attribute__((ext_vector_type(4))) float floatx4;

__device__ __forceinline__ ushort f2bf(float f) {
    union { float f; uint32_t u; } v; v.f = f;
    uint32_t r = v.u + 0x7FFF + ((v.u >> 16) & 1);   // RNE
    return (ushort)(r >> 16);
}

// ---------------- W transpose + cast: Wtb[n=192][k=256] bf16 ----------------
__global__ __launch_bounds__(256) void prep_w(
    const float* __restrict__ Wq, const float* __restrict__ Wk,
    const float* __restrict__ Wv, ushort* __restrict__ Wtb)
{
    const int n = blockIdx.x;                 // 0..191
    const float* W = (n < 64) ? Wq : (n < 128) ? Wk : Wv;
    const int c = n & 63;
    const int k = threadIdx.x;                // 0..255
    Wtb[n * 256 + k] = f2bf(W[k * 64 + c]);
}

// ---------------- QKV projection via MFMA (R4 config) ----------------
// 1024 blocks x 64 rows. 4 waves; wave w owns n-slice [w*48, w*48+48).
// Qb pre-scaled by log2(e)/16 (folds softmax scale + exp2 conversion).
#define XS_STRIDE 264   // 256 + 8 pad (bf16 elems)
__global__ __launch_bounds__(256, 4) void proj_mfma(
    const float* __restrict__ x, const ushort* __restrict__ Wtb,
    ushort* __restrict__ Qb, ushort* __restrict__ Kb, ushort* __restrict__ Vtb)
{
    __shared__ ushort xs[64 * XS_STRIDE];     // 33,792 B
    const int t = threadIdx.x;
    const int blk = blockIdx.x;
    const int64_t row0 = (int64_t)blk * 64;

    const float4* xg = (const float4*)(x + row0 * F_DIM);
    #pragma unroll
    for (int u = 0; u < 8; ++u) {
        const int idx = t + 256 * u;
        const int row = idx >> 5;
        const int c8 = (idx & 31) * 8;
        const float4 a = xg[idx * 2];
        const float4 b = xg[idx * 2 + 1];
        *(ushort4*)&xs[row * XS_STRIDE + c8] =
            make_ushort4(f2bf(a.x), f2bf(a.y), f2bf(a.z), f2bf(a.w));
        *(ushort4*)&xs[row * XS_STRIDE + c8 + 4] =
            make_ushort4(f2bf(b.x), f2bf(b.y), f2bf(b.z), f2bf(b.w));
    }
    __syncthreads();

    const int w = t >> 6, lane = t & 63;
    const int q16 = lane >> 4, l16 = lane & 15;
    const int n0 = w * 48;

    floatx4 acc[4][3];
    #pragma unroll
    for (int mt = 0; mt < 4; ++mt)
        #pragma unroll
        for (int nt = 0; nt < 3; ++nt) acc[mt][nt] = (floatx4){0.f, 0.f, 0.f, 0.f};

    short8 nb[3];
    #pragma unroll
    for (int nt = 0; nt < 3; ++nt)
        nb[nt] = *(const short8*)&Wtb[(n0 + nt * 16 + l16) * 256 + q16 * 8];

    for (int ks = 0; ks < 8; ++ks) {
        short8 cur[3];
        #pragma unroll
        for (int nt = 0; nt < 3; ++nt) cur[nt] = nb[nt];
        if (ks < 7) {
            #pragma unroll
            for (int nt = 0; nt < 3; ++nt)
                nb[nt] = *(const short8*)&Wtb[(n0 + nt * 16 + l16) * 256 + (ks + 1) * 32 + q16 * 8];
        }
        #pragma unroll
        for (int mt = 0; mt < 4; ++mt) {
            const short8 afr = *(const short8*)&xs[(mt * 16 + l16) * XS_STRIDE + ks * 32 + q16 * 8];
            #pragma unroll
            for (int nt = 0; nt < 3; ++nt)
                acc[mt][nt] = __builtin_amdgcn_mfma_f32_16x16x32_bf16(afr, cur[nt], acc[mt][nt], 0, 0, 0);
        }
    }

    const float qscale = 0.0625f * 1.44269504f;
    #pragma unroll
    for (int mt = 0; mt < 4; ++mt) {
        const int64_t g = row0 + mt * 16 + q16 * 4;
        #pragma unroll
        for (int nt = 0; nt < 3; ++nt) {
            const int ntb = n0 + nt * 16;             // wave-uniform
            const int n = ntb + l16;
            if (ntb < 64) {
                #pragma unroll
                for (int r = 0; r < 4; ++r)
                    Qb[(g + r) * 64 + n] = f2bf(acc[mt][nt][r] * qscale);
            } else if (ntb < 128) {
                #pragma unroll
                for (int r = 0; r < 4; ++r)
                    Kb[(g + r) * 64 + (n - 64)] = f2bf(acc[mt][nt][r]);
            } else {
                const int d = n - 128;
                const int ib = (int)(g >> 7);
                const int h = (int)(g & 127);
                *(ushort4*)&Vtb[((int64_t)(ib * 64 + d)) * 128 + h] =
                    make_ushort4(f2bf(acc[mt][nt][0]), f2bf(acc[mt][nt][1]),
                                 f2bf(acc[mt][nt][2]), f2bf(acc[mt][nt][3]));
            }
        }
    }
}

// ---------------- attention via MFMA: S^T form + reg-prefetch pipeline ----
// 1024 blocks, XCD-swizzled: blk = [j:3][b_hi:3][hh:1][xcd:3], b = xcd*8+b_hi.
// 64 p-rows per block, wave owns 16 (p = l16). S^T = K·Q^T; softmax along
// C-rows (2 shfls); P^T chunks through wave-private LDS; O^T = V^T·P^T.
#define KS_STRIDE 68    // 64 + 4 pad
#define VT_STRIDE 132   // 128 + 4 pad
#define PT_STRIDE 40    // 32 + 8 pad (80 B rows: 16B-aligned b128 reads)
__global__ __launch_bounds__(256, 4) void attn_mfma(
    const ushort* __restrict__ Qb, const ushort* __restrict__ Kb,
    const ushort* __restrict__ Vtb, float* __restrict__ out)
{
    __shared__ ushort Ks[128 * KS_STRIDE];   // 17,408 B
    __shared__ ushort Vt[64 * VT_STRIDE];    // 16,896 B
    __shared__ ushort Ps[4][16 * PT_STRIDE]; //  5,120 B  (total 39,424)

    const int t = threadIdx.x;
    const int blk = blockIdx.x;
    const int xcd = blk & 7;
    const int hh  = (blk >> 3) & 1;
    const int bhi = (blk >> 4) & 7;
    const int j   = blk >> 7;
    const int b   = xcd * 8 + bhi;
    const int jb  = j * 64 + b;

    const int w = t >> 6, lane = t & 63;
    const int q16 = lane >> 4, l16 = lane & 15;
    ushort* Psw = &Ps[w][0];

    // Q B-frags (pre-scaled by log2e/16); wave p-rows = hh*64 + w*16 + l16
    const int qrow0 = jb * H_DIM + hh * 64 + w * 16;
    short8 qa[2];
    #pragma unroll
    for (int ks = 0; ks < 2; ++ks)
        qa[ks] = *(const short8*)&Qb[(qrow0 + l16) * 64 + ks * 32 + q16 * 8];

    floatx4 of[4];   // O^T: 4 d-tiles x (16 p)
    #pragma unroll
    for (int mt = 0; mt < 4; ++mt) of[mt] = (floatx4){0.f, 0.f, 0.f, 0.f};

    // prefetch tile i=0 into registers
    uint4 pk[4], pv[4];
    {
        const uint4* ks = (const uint4*)(Kb + (int64_t)b * H_DIM * HS);
        const uint4* vs = (const uint4*)(Vtb + (int64_t)b * HS * H_DIM);
        #pragma unroll
        for (int u = 0; u < 4; ++u) { pk[u] = ks[t + 256 * u]; pv[u] = vs[t + 256 * u]; }
    }

    for (int i = 0; i < N_SEQ; ++i) {
        __syncthreads();   // all waves done reading LDS of prior iter
        #pragma unroll
        for (int u = 0; u < 4; ++u) {
            const int idx = t + 256 * u;
            *(uint4*)&Ks[(idx >> 3) * KS_STRIDE + (idx & 7) * 8] = pk[u];
            *(uint4*)&Vt[(idx >> 4) * VT_STRIDE + (idx & 15) * 8] = pv[u];
        }
        __syncthreads();   // staged tile visible

        if (i < N_SEQ - 1) {   // fire loads for next tile; consumed next iter
            const uint4* ks = (const uint4*)(Kb + ((int64_t)(i + 1) * B_DIM + b) * H_DIM * HS);
            const uint4* vs = (const uint4*)(Vtb + ((int64_t)(i + 1) * B_DIM + b) * HS * H_DIM);
            #pragma unroll
            for (int u = 0; u < 4; ++u) { pk[u] = ks[t + 256 * u]; pv[u] = vs[t + 256 * u]; }
        }

        // ---- S^T = K Q^T : 128(q) x 16(p) per wave, A=K frag, B=Q frag ----
        floatx4 sf[8];
        #pragma unroll
        for (int nt = 0; nt < 8; ++nt) sf[nt] = (floatx4){0.f, 0.f, 0.f, 0.f};
        #pragma unroll
        for (int ks = 0; ks < 2; ++ks)
            #pragma unroll
            for (int nt = 0; nt < 8; ++nt) {
                const short8 ak = *(const short8*)&Ks[(nt * 16 + l16) * KS_STRIDE + ks * 32 + q16 * 8];
                sf[nt] = __builtin_amdgcn_mfma_f32_16x16x32_bf16(ak, qa[ks], sf[nt], 0, 0, 0);
            }

        // ---- softmax along q (C-layout rows): exp2, 2-shfl column sum ----
        #pragma unroll
        for (int nt = 0; nt < 8; ++nt)
            #pragma unroll
            for (int r = 0; r < 4; ++r) sf[nt][r] = __builtin_amdgcn_exp2f(sf[nt][r]);

        float l = 0.f;
        #pragma unroll
        for (int nt = 0; nt < 8; ++nt)
            #pragma unroll
            for (int r = 0; r < 4; ++r) l += sf[nt][r];
        l += __shfl_xor(l, 16);
        l += __shfl_xor(l, 32);
        const float inv = __builtin_amdgcn_rcpf(l);   // per-lane scalar (col p = l16)

        // ---- O^T += V^T P^T, kq-chunked (32 q per chunk) ----
        #pragma unroll
        for (int kq = 0; kq < 4; ++kq) {
            // write P^T chunk: rows p=l16, q-local = tt*16 + q16*4 + r
            #pragma unroll
            for (int tt = 0; tt < 2; ++tt) {
                const int nt = kq * 2 + tt;
                *(ushort4*)&Psw[l16 * PT_STRIDE + tt * 16 + q16 * 4] =
                    make_ushort4(f2bf(sf[nt][0] * inv), f2bf(sf[nt][1] * inv),
                                 f2bf(sf[nt][2] * inv), f2bf(sf[nt][3] * inv));
            }
            const short8 bp = *(const short8*)&Psw[l16 * PT_STRIDE + q16 * 8];
            #pragma unroll
            for (int mt = 0; mt < 4; ++mt) {
                const short8 av = *(const short8*)&Vt[(mt * 16 + l16) * VT_STRIDE + kq * 32 + q16 * 8];
                of[mt] = __builtin_amdgcn_mfma_f32_16x16x32_bf16(av, bp, of[mt], 0, 0, 0);
            }
        }
    }

    // ---- epilogue: O^T C-layout -> float4 stores (4 consecutive d) ----
    #pragma unroll
    for (int mt = 0; mt < 4; ++mt)
        *(float4*)&out[((int64_t)qrow0 + l16) * HS + mt * 16 + q16 * 4] =
            make_float4(of[mt][0], of[mt][1], of[mt][2], of[mt][3]);
}

extern "C" void kernel_launch(void* const* d_in, const int* in_sizes, int n_in,
                              void* d_out, int out_size, void* d_ws, size_t ws_size,
                              hipStream_t stream)
{
    const float* x  = (const float*)d_in[0];
    const float* Wq = (const float*)d_in[1];
    const float* Wk = (const float*)d_in[2];
    const float* Wv = (const float*)d_in[3];
    float* out = (float*)d_out;

    const size_t qkv = (size_t)N_SEQ * B_DIM * H_DIM * HS;   // 4,194,304 elems
    ushort* Qb  = (ushort*)d_ws;
    ushort* Kb  = Qb + qkv;
    ushort* Vtb = Kb + qkv;
    ushort* Wtb = Vtb + qkv;                                 // 192*256 elems

    prep_w<<<192, 256, 0, stream>>>(Wq, Wk, Wv, Wtb);
    proj_mfma<<<(N_SEQ * B_DIM * H_DIM) / 64, 256, 0, stream>>>(x, Wtb, Qb, Kb, Vtb);
    attn_mfma<<<N_SEQ * B_DIM * 2, 256, 0, stream>>>(Qb, Kb, Vtb, out);
}

// Round 7
// 148.734 us; speedup vs baseline: 1.6104x; 1.3809x over previous
//
#include <hip/hip_runtime.h>
#include <cstdint>

#define N_SEQ 8
#define B_DIM 64
#define H_DIM 128
#define F_DIM 256
#define HS 64

typedef __attribute__((ext_vector_type(8))) short short8;
typedef __attribute__((ext_vector_type(4))) float floatx4;

__device__ __forceinline__ ushort f2bf(float f) {
    union { float f; uint32_t u; } v; v.f = f;
    uint32_t r = v.u + 0x7FFF + ((v.u >> 16) & 1);   // RNE
    return (ushort)(r >> 16);
}

// async 16B-per-lane global -> LDS (wave-uniform LDS base + lane*16)
__device__ __forceinline__ void async_ld16(const ushort* g, ushort* lds) {
    __builtin_amdgcn_global_load_lds(
        (const __attribute__((address_space(1))) unsigned int*)g,
        (__attribute__((address_space(3))) unsigned int*)lds,
        16, 0, 0);
}

// ---------------- W transpose + cast: Wtb[n=192][k=256] bf16 ----------------
__global__ __launch_bounds__(256) void prep_w(
    const float* __restrict__ Wq, const float* __restrict__ Wk,
    const float* __restrict__ Wv, ushort* __restrict__ Wtb)
{
    const int n = blockIdx.x;                 // 0..191
    const float* W = (n < 64) ? Wq : (n < 128) ? Wk : Wv;
    const int c = n & 63;
    const int k = threadIdx.x;                // 0..255
    Wtb[n * 256 + k] = f2bf(W[k * 64 + c]);
}

// ---------------- QKV projection via MFMA (R4 config, unchanged) ----------
#define XS_STRIDE 264   // 256 + 8 pad (bf16 elems)
__global__ __launch_bounds__(256, 4) void proj_mfma(
    const float* __restrict__ x, const ushort* __restrict__ Wtb,
    ushort* __restrict__ Qb, ushort* __restrict__ Kb, ushort* __restrict__ Vtb)
{
    __shared__ ushort xs[64 * XS_STRIDE];     // 33,792 B
    const int t = threadIdx.x;
    const int blk = blockIdx.x;
    const int64_t row0 = (int64_t)blk * 64;

    const float4* xg = (const float4*)(x + row0 * F_DIM);
    #pragma unroll
    for (int u = 0; u < 8; ++u) {
        const int idx = t + 256 * u;
        const int row = idx >> 5;
        const int c8 = (idx & 31) * 8;
        const float4 a = xg[idx * 2];
        const float4 b = xg[idx * 2 + 1];
        *(ushort4*)&xs[row * XS_STRIDE + c8] =
            make_ushort4(f2bf(a.x), f2bf(a.y), f2bf(a.z), f2bf(a.w));
        *(ushort4*)&xs[row * XS_STRIDE + c8 + 4] =
            make_ushort4(f2bf(b.x), f2bf(b.y), f2bf(b.z), f2bf(b.w));
    }
    __syncthreads();

    const int w = t >> 6, lane = t & 63;
    const int q16 = lane >> 4, l16 = lane & 15;
    const int n0 = w * 48;

    floatx4 acc[4][3];
    #pragma unroll
    for (int mt = 0; mt < 4; ++mt)
        #pragma unroll
        for (int nt = 0; nt < 3; ++nt) acc[mt][nt] = (floatx4){0.f, 0.f, 0.f, 0.f};

    short8 nb[3];
    #pragma unroll
    for (int nt = 0; nt < 3; ++nt)
        nb[nt] = *(const short8*)&Wtb[(n0 + nt * 16 + l16) * 256 + q16 * 8];

    for (int ks = 0; ks < 8; ++ks) {
        short8 cur[3];
        #pragma unroll
        for (int nt = 0; nt < 3; ++nt) cur[nt] = nb[nt];
        if (ks < 7) {
            #pragma unroll
            for (int nt = 0; nt < 3; ++nt)
                nb[nt] = *(const short8*)&Wtb[(n0 + nt * 16 + l16) * 256 + (ks + 1) * 32 + q16 * 8];
        }
        #pragma unroll
        for (int mt = 0; mt < 4; ++mt) {
            const short8 afr = *(const short8*)&xs[(mt * 16 + l16) * XS_STRIDE + ks * 32 + q16 * 8];
            #pragma unroll
            for (int nt = 0; nt < 3; ++nt)
                acc[mt][nt] = __builtin_amdgcn_mfma_f32_16x16x32_bf16(afr, cur[nt], acc[mt][nt], 0, 0, 0);
        }
    }

    const float qscale = 0.0625f * 1.44269504f;
    #pragma unroll
    for (int mt = 0; mt < 4; ++mt) {
        const int64_t g = row0 + mt * 16 + q16 * 4;
        #pragma unroll
        for (int nt = 0; nt < 3; ++nt) {
            const int ntb = n0 + nt * 16;             // wave-uniform
            const int n = ntb + l16;
            if (ntb < 64) {
                #pragma unroll
                for (int r = 0; r < 4; ++r)
                    Qb[(g + r) * 64 + n] = f2bf(acc[mt][nt][r] * qscale);
            } else if (ntb < 128) {
                #pragma unroll
                for (int r = 0; r < 4; ++r)
                    Kb[(g + r) * 64 + (n - 64)] = f2bf(acc[mt][nt][r]);
            } else {
                const int d = n - 128;
                const int ib = (int)(g >> 7);
                const int h = (int)(g & 127);
                *(ushort4*)&Vtb[((int64_t)(ib * 64 + d)) * 128 + h] =
                    make_ushort4(f2bf(acc[mt][nt][0]), f2bf(acc[mt][nt][1]),
                                 f2bf(acc[mt][nt][2]), f2bf(acc[mt][nt][3]));
            }
        }
    }
}

// ---------------- attention: async global_load_lds + LDS double-buffer ----
// 512 blocks (one per jb, 2/CU). Frag-linear LDS tiles (16 frags x 1 KB).
// Wave w handles p-halves {w*16+l16, 64+w*16+l16}; K/V frags shared across
// halves. One barrier per i-iteration; stage(i+1) in flight under compute.
#define PT_STRIDE 40    // 32 + 8 pad (80 B rows, 16B-aligned b128 reads)
__global__ __launch_bounds__(256, 2) void attn_mfma(
    const ushort* __restrict__ Qb, const ushort* __restrict__ Kb,
    const ushort* __restrict__ Vtb, float* __restrict__ out)
{
    __shared__ ushort Ks[2][8192];            // 2 x 16 KB, frag-linear
    __shared__ ushort Vt[2][8192];            // 2 x 16 KB, frag-linear
    __shared__ ushort Ps[4][2][16 * PT_STRIDE];  // 10,240 B

    const int t = threadIdx.x;
    const int blk = blockIdx.x;
    const int b  = ((blk & 7) << 3) | ((blk >> 3) & 7);   // XCD-major b
    const int j  = blk >> 6;
    const int jb = j * 64 + b;

    const int w = t >> 6, lane = t & 63;
    const int q16 = lane >> 4, l16 = lane & 15;

    // staging frag assignment: fi = w*4+u
    // K frag fi: ks=fi>>3, nt=fi&7 ; lane elem = (nt*16+l16)*64 + ks*32 + q16*8
    // V frag fi: kq=fi>>2, mt=fi&3 ; lane elem = (mt*16+l16)*128 + kq*32 + q16*8
    int koff[4], voff[4], ldsoff[4];
    #pragma unroll
    for (int u = 0; u < 4; ++u) {
        const int fi = w * 4 + u;
        koff[u] = ((fi & 7) * 16 + l16) * 64 + (fi >> 3) * 32 + q16 * 8;
        voff[u] = ((fi & 3) * 16 + l16) * 128 + (fi >> 2) * 32 + q16 * 8;
        ldsoff[u] = fi * 512;   // ushorts
    }

    // Q B-frags for both halves (Qb pre-scaled by log2e/16)
    const int prow = jb * H_DIM + w * 16 + l16;
    short8 qa[2][2];
    #pragma unroll
    for (int hh = 0; hh < 2; ++hh)
        #pragma unroll
        for (int ks = 0; ks < 2; ++ks)
            qa[hh][ks] = *(const short8*)&Qb[(prow + hh * 64) * 64 + ks * 32 + q16 * 8];

    floatx4 of[2][4];
    #pragma unroll
    for (int hh = 0; hh < 2; ++hh)
        #pragma unroll
        for (int mt = 0; mt < 4; ++mt) of[hh][mt] = (floatx4){0.f, 0.f, 0.f, 0.f};

    // ---- prologue: stage tile 0 into buffer 0 ----
    {
        const ushort* kg = Kb + ((0 * B_DIM + b) << 13);
        const ushort* vg = Vtb + ((0 * B_DIM + b) << 13);
        #pragma unroll
        for (int u = 0; u < 4; ++u) {
            const int lo = __builtin_amdgcn_readfirstlane(ldsoff[u]);
            async_ld16(kg + koff[u], &Ks[0][lo]);
            async_ld16(vg + voff[u], &Vt[0][lo]);
        }
    }

    for (int i = 0; i < N_SEQ; ++i) {
        const int buf = i & 1;
        __syncthreads();   // drains stage(i) loads; protects buf's prior readers

        if (i < N_SEQ - 1) {   // async stage of tile i+1; lands during compute
            const ushort* kg = Kb + (((i + 1) * B_DIM + b) << 13);
            const ushort* vg = Vtb + (((i + 1) * B_DIM + b) << 13);
            #pragma unroll
            for (int u = 0; u < 4; ++u) {
                const int lo = __builtin_amdgcn_readfirstlane(ldsoff[u]);
                async_ld16(kg + koff[u], &Ks[buf ^ 1][lo]);
                async_ld16(vg + voff[u], &Vt[buf ^ 1][lo]);
            }
        }

        // ---- S^T = K Q^T for both p-halves, sharing K frags ----
        floatx4 sf[2][8];
        #pragma unroll
        for (int hh = 0; hh < 2; ++hh)
            #pragma unroll
            for (int nt = 0; nt < 8; ++nt) sf[hh][nt] = (floatx4){0.f, 0.f, 0.f, 0.f};
        #pragma unroll
        for (int ks = 0; ks < 2; ++ks)
            #pragma unroll
            for (int nt = 0; nt < 8; ++nt) {
                const short8 ak = *(const short8*)&Ks[buf][(ks * 8 + nt) * 512 + lane * 8];
                sf[0][nt] = __builtin_amdgcn_mfma_f32_16x16x32_bf16(ak, qa[0][ks], sf[0][nt], 0, 0, 0);
                sf[1][nt] = __builtin_amdgcn_mfma_f32_16x16x32_bf16(ak, qa[1][ks], sf[1][nt], 0, 0, 0);
            }

        // ---- softmax along q (cols across 4 quads): exp2, 2-shfl sum ----
        float inv[2];
        #pragma unroll
        for (int hh = 0; hh < 2; ++hh) {
            float l = 0.f;
            #pragma unroll
            for (int nt = 0; nt < 8; ++nt)
                #pragma unroll
                for (int r = 0; r < 4; ++r) {
                    sf[hh][nt][r] = __builtin_amdgcn_exp2f(sf[hh][nt][r]);
                    l += sf[hh][nt][r];
                }
            l += __shfl_xor(l, 16);
            l += __shfl_xor(l, 32);
            inv[hh] = __builtin_amdgcn_rcpf(l);
        }

        // ---- O^T += V^T P^T, kq-chunked, sharing V frags across halves ----
        #pragma unroll
        for (int kq = 0; kq < 4; ++kq) {
            #pragma unroll
            for (int hh = 0; hh < 2; ++hh)
                #pragma unroll
                for (int tt = 0; tt < 2; ++tt) {
                    const int nt = kq * 2 + tt;
                    *(ushort4*)&Ps[w][hh][l16 * PT_STRIDE + tt * 16 + q16 * 4] =
                        make_ushort4(f2bf(sf[hh][nt][0] * inv[hh]),
                                     f2bf(sf[hh][nt][1] * inv[hh]),
                                     f2bf(sf[hh][nt][2] * inv[hh]),
                                     f2bf(sf[hh][nt][3] * inv[hh]));
                }
            const short8 bp0 = *(const short8*)&Ps[w][0][l16 * PT_STRIDE + q16 * 8];
            const short8 bp1 = *(const short8*)&Ps[w][1][l16 * PT_STRIDE + q16 * 8];
            #pragma unroll
            for (int mt = 0; mt < 4; ++mt) {
                const short8 av = *(const short8*)&Vt[buf][(kq * 4 + mt) * 512 + lane * 8];
                of[0][mt] = __builtin_amdgcn_mfma_f32_16x16x32_bf16(av, bp0, of[0][mt], 0, 0, 0);
                of[1][mt] = __builtin_amdgcn_mfma_f32_16x16x32_bf16(av, bp1, of[1][mt], 0, 0, 0);
            }
        }
    }

    // ---- epilogue: O^T C-layout -> float4 stores (4 consecutive d) ----
    #pragma unroll
    for (int hh = 0; hh < 2; ++hh)
        #pragma unroll
        for (int mt = 0; mt < 4; ++mt)
            *(float4*)&out[(int64_t)(prow + hh * 64) * HS + mt * 16 + q16 * 4] =
                make_float4(of[hh][mt][0], of[hh][mt][1], of[hh][mt][2], of[hh][mt][3]);
}

extern "C" void kernel_launch(void* const* d_in, const int* in_sizes, int n_in,
                              void* d_out, int out_size, void* d_ws, size_t ws_size,
                              hipStream_t stream)
{
    const float* x  = (const float*)d_in[0];
    const float* Wq = (const float*)d_in[1];
    const float* Wk = (const float*)d_in[2];
    const float* Wv = (const float*)d_in[3];
    float* out = (float*)d_out;

    const size_t qkv = (size_t)N_SEQ * B_DIM * H_DIM * HS;   // 4,194,304 elems
    ushort* Qb  = (ushort*)d_ws;
    ushort* Kb  = Qb + qkv;
    ushort* Vtb = Kb + qkv;
    ushort* Wtb = Vtb + qkv;                                 // 192*256 elems

    prep_w<<<192, 256, 0, stream>>>(Wq, Wk, Wv, Wtb);
    proj_mfma<<<(N_SEQ * B_DIM * H_DIM) / 64, 256, 0, stream>>>(x, Wtb, Qb, Kb, Vtb);
    attn_mfma<<<N_SEQ * B_DIM, 256, 0, stream>>>(Qb, Kb, Vtb, out);
}